// Round 6
// baseline (269.123 us; speedup 1.0000x reference)
//
#include <hip/hip_runtime.h>
#include <stdint.h>

typedef unsigned int u32;
typedef unsigned long long u64;

#define HH 256
#define WW 512
#define HW (HH*WW)          // 131072
#define N2 (2*HW)           // 262144 per branch
#define NT (2*N2)           // 524288 total boxes
#define TOPK 4096
#define SCORE_THR 0.2f
#define NMS_THR 0.15f

// ---- workspace layout (bytes) ----
// [0, 2MB)  keys -> reused as rank partials (256 KB) -> reused as NMS mask
#define OFF_KEYS   0ull
#define OFF_GHIST  ((size_t)NT*4)                  // u32[1024] = 4 KB @ 2,097,152
#define OFF_GHIST2 (OFF_GHIST + 4096)              // u32[1024] = 4 KB
#define OFF_CNT    (OFF_GHIST2 + 4096)             // u32 cnt, u32 done, pad to 16
#define OFF_VALIDM (OFF_CNT + 16)                  // u64[64] = 512 B
#define OFF_CAND   (OFF_VALIDM + 512)              // u64[8192] = 64 KB
#define OFF_STAND  OFF_CAND                        // float4[4096] overlays cand
#define OFF_SELIDX (OFF_CAND + 65536)              // u32[4096]
#define OFF_SELSC  (OFF_SELIDX + (size_t)TOPK*4)   // f32[4096]
#define OFF_TDIAG  (OFF_SELSC + (size_t)TOPK*4)    // u64[4096] = 32 KB @ 2,204,176
// end = 2,236,944 B < 2,261,008 proven in R6/R8
#define ZERO_BYTES (4096 + 4096 + 16)              // ghist + ghist2 + cnt/done
#define RANK_J 8                                   // j-slices for rank counting

// k_nms staging geometry
#define NMSW 4                                     // waves
#define RPW 16                                     // rows per wave
#define WREG_U64 1088                              // per-wave region: 1024 rows + 64 tdiag
#define SLOT_U64 (NMSW * WREG_U64)                 // 4352 u64 = 34 KB per ring slot

// orderable key for float (descending sortable as unsigned)
__device__ __forceinline__ u32 f2ord(float f) {
    u32 b = __float_as_uint(f);
    return (b & 0x80000000u) ? ~b : (b | 0x80000000u);
}

// ---------------- K1: scores -> keys + per-block LDS hist1 -> global -------
__global__ void __launch_bounds__(1024) k_keys(const float* __restrict__ psm_v,
                                               const float* __restrict__ psm_i,
                                               u32* __restrict__ keys,
                                               u32* __restrict__ ghist) {
    __shared__ u32 lh[1024];
    int t = threadIdx.x;
    lh[t] = 0;
    __syncthreads();
    int n = blockIdx.x * 1024 + t;
    int br = n >> 18;
    int m  = n & (N2 - 1);
    int a  = m & 1;
    int hw = m >> 1;
    const float* psm = br ? psm_i : psm_v;
    float x = psm[a * HW + hw];
    float s = 1.0f / (1.0f + __builtin_expf(-x));   // mirror ref f32 sigmoid
    u32 key = 0u;
    if (s > SCORE_THR) key = f2ord(s);
    keys[n] = key;
    if (key) atomicAdd(&lh[key >> 22], 1u);
    __syncthreads();
    u32 c = lh[t];
    if (c) atomicAdd(&ghist[t], c);
}

// Wave-0 suffix-scan pivot over a 1024-entry count array (16 entries/lane).
// suffix(b) non-increasing -> unique crossing (lane,j) writes result (race-free).
__device__ __forceinline__ void pivot1024(const u32* __restrict__ arr, u32 target,
                                          u32* out_bin, u32* out_next, int l) {
    u32 h[16], loc[16];
#pragma unroll
    for (int j = 0; j < 16; ++j) h[j] = arr[l * 16 + j];
    loc[15] = h[15];
#pragma unroll
    for (int j = 14; j >= 0; --j) loc[j] = loc[j + 1] + h[j];
    u32 T = loc[0];
    u32 incl = T;
#pragma unroll
    for (int d = 1; d < 64; d <<= 1) {
        u32 v = __shfl_down(incl, d);
        if (l + d < 64) incl += v;
    }
    u32 E = incl - T;                      // sum over lanes > l
#pragma unroll
    for (int j = 0; j < 16; ++j) {
        u32 S  = loc[j] + E;
        u32 Sn = (j < 15 ? loc[j + 1] : 0u) + E;
        if (S >= target && Sn < target) {
            *out_bin = (u32)(l * 16 + j);
            *out_next = Sn;
        }
    }
}

// ---------------- K2: hist2 over key>>12 within pivot-1 bin (512 blocks) ----
__global__ void __launch_bounds__(1024) k_hist2(const u32* __restrict__ ghist,
                                                const u32* __restrict__ keys,
                                                u32* __restrict__ ghist2) {
    __shared__ u32 lh[1024];
    __shared__ u32 b1_sh;
    int tid = threadIdx.x;
    lh[tid] = 0;
    if (tid < 64) {
        u32 bin = 0xFFFFFFFFu, nxt = 0;
        pivot1024(ghist, (u32)TOPK, &bin, &nxt, tid);
        if (bin != 0xFFFFFFFFu) b1_sh = bin;    // winner-lane writes
    }
    __syncthreads();
    u32 b1 = b1_sh;
    int n = blockIdx.x * 1024 + tid;
    u32 key = keys[n];
    if ((key >> 22) == b1) atomicAdd(&lh[(key >> 12) & 1023u], 1u);
    __syncthreads();
    u32 c = lh[tid];
    if (c) atomicAdd(&ghist2[tid], c);
}

// ---------------- K3: compact at 20-bit cut (512 blocks) --------------------
__global__ void __launch_bounds__(1024) k_collect(const u32* __restrict__ ghist,
                                                  const u32* __restrict__ ghist2,
                                                  const u32* __restrict__ keys,
                                                  u64* __restrict__ cand,
                                                  u32* __restrict__ cnt) {
    __shared__ u32 b1_sh, t2_sh, b2_sh;
    int tid = threadIdx.x;
    if (tid < 64) {
        u32 bin = 0xFFFFFFFFu, nxt = 0;
        pivot1024(ghist, (u32)TOPK, &bin, &nxt, tid);
        if (bin != 0xFFFFFFFFu) { b1_sh = bin; t2_sh = (u32)TOPK - nxt; }
    }
    __syncthreads();
    if (tid < 64) {
        u32 bin = 0xFFFFFFFFu, nxt = 0;
        pivot1024(ghist2, t2_sh, &bin, &nxt, tid);
        if (bin != 0xFFFFFFFFu) b2_sh = bin;
    }
    __syncthreads();
    u32 thr20 = (b1_sh << 10) | b2_sh;
    int n = blockIdx.x * 1024 + tid;
    u32 key = keys[n];
    if ((key >> 12) >= thr20) {
        u32 pos = atomicAdd(cnt, 1u);
        if (pos < 8192u)
            cand[pos] = ((u64)key << 32) | (u64)(u32)(~(u32)n);
    }
}

// ---------------- K4: partial rank counts + last-block scatter --------------
// rank(i) = #{j : cand[j] > cand[i]} decomposes over j-slices. Block (bi,bj)
// stages j-slice bj in LDS, counts for its 256 i's, writes partial[bj][i]
// (unconditional, exactly-one-writer). The LAST block to finish (device-scope
// atomic on done counter, decoupled-lookback pattern w/ __threadfence) sums
// partials and scatters sel_idx — saves the separate k_scatter launch.
__global__ void __launch_bounds__(256) k_rank1(const u64* __restrict__ cand,
                                               const u32* __restrict__ cnt,
                                               u32* __restrict__ partial,
                                               u32* __restrict__ done,
                                               u32* __restrict__ sel_idx) {
    __shared__ u64 tile[1024];
    __shared__ u32 lastsh;
    int tid = threadIdx.x;
    int i = blockIdx.x * 256 + tid;
    u32 base = blockIdx.y * 1024u;
    u32 c = *cnt;
    if (c > 8192u) c = 8192u;
    u64 my = (i < (int)c) ? cand[i] : 0ull;
#pragma unroll
    for (int k = 0; k < 4; ++k) {
        u32 idx = base + tid + k * 256;
        tile[tid + k * 256] = (idx < c) ? cand[idx] : 0ull;
    }
    __syncthreads();
    u32 lim = (c > base) ? ((c - base < 1024u) ? (c - base) : 1024u) : 0u;
    u32 r = 0;
#pragma unroll 4
    for (u32 k = 0; k < lim; ++k) r += (tile[k] > my) ? 1u : 0u;
    partial[blockIdx.y * 8192 + i] = r;
    __threadfence();                       // release: partials device-visible
    __syncthreads();
    if (tid == 0)
        lastsh = (atomicAdd(done, 1u) == (u32)(32 * RANK_J - 1)) ? 1u : 0u;
    __syncthreads();
    if (lastsh) {
        __threadfence();                   // acquire before reading partials
        for (u32 it = tid; it < c; it += 256u) {
            u32 rank = 0;
#pragma unroll
            for (int bj = 0; bj < RANK_J; ++bj) rank += partial[bj * 8192 + it];
            if (rank < (u32)TOPK)
                sel_idx[rank] = ~((u32)(cand[it] & 0xFFFFFFFFull));
        }
    }
}

// ---------------- box math helpers (mirror the jax reference) ---------------
__device__ __forceinline__ void box_corners(const float b[7], float cx[8], float cy[8], float cz[8]) {
    const float sx[8] = {0.5f,0.5f,-0.5f,-0.5f,0.5f,0.5f,-0.5f,-0.5f};
    const float sy[8] = {0.5f,-0.5f,-0.5f,0.5f,0.5f,-0.5f,-0.5f,0.5f};
    const float sz[8] = {-0.5f,-0.5f,-0.5f,-0.5f,0.5f,0.5f,0.5f,0.5f};
    float c = __builtin_cosf(b[6]), s = __builtin_sinf(b[6]);
#pragma unroll
    for (int k = 0; k < 8; k++) {
        float x = b[5] * sx[k], y = b[4] * sy[k], z = b[3] * sz[k];
        cx[k] = x * c - y * s + b[0];
        cy[k] = x * s + y * c + b[1];
        cz[k] = z + b[2];
    }
}

__device__ __forceinline__ void proj_T(const float* __restrict__ T, float cx[8], float cy[8], float cz[8]) {
#pragma unroll
    for (int k = 0; k < 8; k++) {
        float x = cx[k], y = cy[k], z = cz[k];
        cx[k] = T[0] * x + T[1] * y + T[2]  * z + T[3];
        cy[k] = T[4] * x + T[5] * y + T[6]  * z + T[7];
        cz[k] = T[8] * x + T[9] * y + T[10] * z + T[11];
    }
}

__device__ __forceinline__ void corner_to_center(const float cx[8], const float cy[8], const float cz[8], float b[7]) {
    float mx = 0.f, my = 0.f, mz = 0.f;
#pragma unroll
    for (int k = 0; k < 8; k++) { mx += cx[k]; my += cy[k]; mz += cz[k]; }
    mx *= 0.125f; my *= 0.125f; mz *= 0.125f;
    float htop = (cz[4] + cz[5] + cz[6] + cz[7]) * 0.25f;
    float hbot = (cz[0] + cz[1] + cz[2] + cz[3]) * 0.25f;
    const int lA[4] = {0,1,4,5}, lB[4] = {3,2,7,6};
    const int wA[4] = {0,3,4,7}, wB[4] = {1,2,5,6};
    float l = 0.f, w = 0.f, dx = 0.f, dy = 0.f;
#pragma unroll
    for (int i = 0; i < 4; i++) {
        float ax = cx[lA[i]] - cx[lB[i]];
        float ay = cy[lA[i]] - cy[lB[i]];
        l += __builtin_sqrtf(ax * ax + ay * ay);
        dx += ax; dy += ay;
    }
#pragma unroll
    for (int i = 0; i < 4; i++) {
        float ax = cx[wA[i]] - cx[wB[i]];
        float ay = cy[wA[i]] - cy[wB[i]];
        w += __builtin_sqrtf(ax * ax + ay * ay);
    }
    b[0] = mx; b[1] = my; b[2] = mz;
    b[3] = htop - hbot;
    b[4] = w * 0.25f;
    b[5] = l * 0.25f;
    b[6] = atan2f(dy, dx);
}

// ---------------- K5: decode boxes -> out corners + standup + validm --------
__global__ void __launch_bounds__(64) k_boxes(const float* __restrict__ anchors,
                                              const float* __restrict__ psm_v,
                                              const float* __restrict__ psm_i,
                                              const float* __restrict__ rm_v,
                                              const float* __restrict__ rm_i,
                                              const float* __restrict__ tproj,
                                              const float* __restrict__ tego,
                                              const u32* __restrict__ sel_idx,
                                              float* __restrict__ sel_sc,
                                              float* __restrict__ out,
                                              float4* __restrict__ stand,
                                              u64* __restrict__ validm) {
    int k = blockIdx.x * blockDim.x + threadIdx.x;
    if (k >= TOPK) return;
    int n = (int)(sel_idx[k] & (u32)(NT - 1));
    int br = n >> 18;
    int m  = n & (N2 - 1);
    int a  = m & 1;
    int hw = m >> 1;

    const float* psm = br ? psm_i : psm_v;
    float xs = psm[a * HW + hw];
    float s  = 1.0f / (1.0f + __builtin_expf(-xs));
    sel_sc[k] = (s > SCORE_THR) ? s : -1.0f;
    u64 vbits = __ballot(s > SCORE_THR);
    if ((threadIdx.x & 63) == 0) validm[k >> 6] = vbits;   // one word per wave

    const float* rm = br ? rm_i : rm_v;
    float d[7];
#pragma unroll
    for (int j = 0; j < 7; j++) d[j] = rm[(a * 7 + j) * HW + hw];
    const float* anc = anchors + (size_t)m * 7;
    float a0 = anc[0], a1 = anc[1], a2 = anc[2], a3 = anc[3], a4 = anc[4], a5 = anc[5], a6 = anc[6];
    float ad = __builtin_sqrtf(a4 * a4 + a5 * a5);
    float b[7];
    b[0] = d[0] * ad + a0;
    b[1] = d[1] * ad + a1;
    b[2] = d[2] * a3 + a2;
    b[3] = __builtin_expf(d[3]) * a3;
    b[4] = __builtin_expf(d[4]) * a4;
    b[5] = __builtin_expf(d[5]) * a5;
    b[6] = d[6] + a6;

    if (br) {  // infrared branch: corners -> t_proj -> back to center form
        float cx[8], cy[8], cz[8];
        box_corners(b, cx, cy, cz);
        proj_T(tproj, cx, cy, cz);
        corner_to_center(cx, cy, cz, b);
    }

    float cx[8], cy[8], cz[8];
    box_corners(b, cx, cy, cz);
    proj_T(tego, cx, cy, cz);

    float mnx = cx[0], mny = cy[0], mxx = cx[0], mxy = cy[0];
#pragma unroll
    for (int c = 0; c < 8; c++) {
        out[(size_t)k * 25 + c * 3 + 0] = cx[c];
        out[(size_t)k * 25 + c * 3 + 1] = cy[c];
        out[(size_t)k * 25 + c * 3 + 2] = cz[c];
        mnx = fminf(mnx, cx[c]); mny = fminf(mny, cy[c]);
        mxx = fmaxf(mxx, cx[c]); mxy = fmaxf(mxy, cy[c]);
    }
    stand[k] = make_float4(mnx, mny, mxx, mxy);
}

// ---------------- K6: fused suppression mask (blocks 0..1023) +
//                  transposed intra-chunk words (blocks 1024..1039) ----------
__global__ void __launch_bounds__(256) k_maskdiag(const float4* __restrict__ stand,
                                                  u64* __restrict__ mask,
                                                  u64* __restrict__ tdiag) {
    __shared__ float4 sb[256];
    int bid = blockIdx.x;
    if (bid < 1024) {
        int i = bid * 4 + (threadIdx.x >> 6);
        int t = threadIdx.x & 63;
        int w0 = i >> 6;                    // chunks below diagonal are all-zero
        float4 bi = stand[i];
        float areai = (bi.z - bi.x) * (bi.w - bi.y);
        u64 myword = 0ull;
        for (int w = w0; w < 64; ++w) {
            int j = w * 64 + t;
            float4 bj = stand[j];
            float areaj = (bj.z - bj.x) * (bj.w - bj.y);
            float ltx = fmaxf(bi.x, bj.x), lty = fmaxf(bi.y, bj.y);
            float rbx = fminf(bi.z, bj.z), rby = fminf(bi.w, bj.w);
            float iw = fmaxf(rbx - ltx, 0.0f), ih = fmaxf(rby - lty, 0.0f);
            float inter = iw * ih;
            float iou = inter / (areai + areaj - inter + 1e-6f);
            bool sup = (iou > NMS_THR) && (j > i);
            u64 bits = __ballot(sup);
            if (t == w) myword = bits;
        }
        mask[(size_t)i * 64 + t] = myword;
    } else {
        // diag part: 16 blocks x 4 chunks. Bit-identical IoU math to mask part.
        int d = bid - 1024;
        int tid = threadIdx.x;
        sb[tid] = stand[d * 256 + tid];     // coalesced stage of 4 chunks
        __syncthreads();
        int sub = tid >> 6, l = tid & 63;
        float4 me = sb[sub * 64 + l];
        float aream = (me.z - me.x) * (me.w - me.y);
        u64 T = 0ull;
        for (int j = 0; j < 64; ++j) {
            float4 bj = sb[sub * 64 + j];            // suppressor candidate
            float areaj = (bj.z - bj.x) * (bj.w - bj.y);
            float ltx = fmaxf(bj.x, me.x), lty = fmaxf(bj.y, me.y);
            float rbx = fminf(bj.z, me.z), rby = fminf(bj.w, me.w);
            float iw = fmaxf(rbx - ltx, 0.0f), ih = fmaxf(rby - lty, 0.0f);
            float inter = iw * ih;
            float iou = inter / (areaj + aream - inter + 1e-6f);
            bool sup = (iou > NMS_THR) && (j < l);
            T |= sup ? (1ull << j) : 0ull;
        }
        tdiag[(size_t)(d * 4 + sub) * 64 + l] = T;
    }
}

// ---------------- K8: 4-wave greedy NMS, double-pipelined (DMA + LDS->VGPR) -
// v6: v5 hid the HBM->LDS hop but issued ~17 LDS reads per chunk AFTER the
// barrier (~1500cy of exposed LDS latency on the serial path). Now rows(B+1)
// + Tl(B+1) are read into VGPRs DURING chunk B (double-buffered rowA/rowB,
// static indexing). vmcnt discipline: refill issued AFTER vmcnt(9) so the
// wait guarantees stage(B+1) complete with only stage(B+2) in flight; slot
// arithmetic uses slot(B+3)==slot(B) (mod 3) so the refill overwrites the
// already-consumed current slot. Post-barrier path: sp read + chain + fold.
__device__ __forceinline__ u64 readlane64(u64 v, int lane) {
    u32 lo = (u32)__builtin_amdgcn_readlane((int)(u32)v, lane);
    u32 hi = (u32)__builtin_amdgcn_readlane((int)(u32)(v >> 32), lane);
    return ((u64)hi << 32) | (u64)lo;
}

__device__ __forceinline__ void nms_stage(const u64* __restrict__ mask,
                                          const u64* __restrict__ tdiag,
                                          int c, int sw, int l, u64* wb) {
    // lane l covers words 2(l&31), 2(l&31)+1; both < c -> provably zero, skip
    bool act = (2 * (l & 31) + 1) >= c;
    const u64* gb = mask + (size_t)c * 4096 + (size_t)(sw * RPW) * 64 + (size_t)l * 2;
    if (act) {
#pragma unroll
        for (int k = 0; k < 8; ++k) {
            __builtin_amdgcn_global_load_lds(
                (const __attribute__((address_space(1))) void*)(gb + (size_t)k * 128),
                (__attribute__((address_space(3))) void*)(wb + (size_t)k * 128), 16, 0, 0);
        }
    }
    if (l < 32) {   // tdiag row c (512B) contiguous into wb+1024
        __builtin_amdgcn_global_load_lds(
            (const __attribute__((address_space(1))) void*)(tdiag + (size_t)c * 64 + (size_t)l * 2),
            (__attribute__((address_space(3))) void*)(wb + 1024), 16, 0, 0);
    }
}

__device__ __forceinline__ void nms_ldrows(const u64* wb, int l,
                                           u64 (&rows)[RPW], u64& Tl) {
    Tl = wb[1024 + l];
#pragma unroll
    for (int k = 0; k < RPW; ++k) rows[k] = wb[(size_t)k * 64 + l];
}

// VMC: 9 = steady-state (stage B+1 done, B+2 may fly), 0 = drain, -1 = none
template<int VMC, bool REFILL, bool PRELOAD>
__device__ __forceinline__ void nms_chunk(int B, int l, int sw,
                                          const u64 (&rows)[RPW], u64 Tl,
                                          u64 (&nrows)[RPW], u64& nTl,
                                          u64* wb_cur, u64* wb_next,
                                          u64 vreg, volatile u64* sh,
                                          u64& remv, u64& keep,
                                          const u64* __restrict__ mask,
                                          const u64* __restrict__ tdiag) {
    // ---- exchange: combine 4 partial remv words for chunk B via LDS ----
    u64 x = readlane64(remv, B);
    if (l == 0) sh[(B & 1) * NMSW + sw] = x;
    __asm__ volatile("" ::: "memory");
    __builtin_amdgcn_s_waitcnt(0xC07F);      // lgkmcnt(0): ds ops committed
    __builtin_amdgcn_s_barrier();            // raw barrier: NO vmcnt drain
    __asm__ volatile("" ::: "memory");
    if constexpr (VMC == 9) __builtin_amdgcn_s_waitcnt(0x0F79);  // vmcnt(9)
    else if constexpr (VMC == 0) __builtin_amdgcn_s_waitcnt(0x0F70);
    __builtin_amdgcn_sched_barrier(0);
    __asm__ volatile("" ::: "memory");
    if constexpr (REFILL) nms_stage(mask, tdiag, B + 3, sw, l, wb_cur);
    if constexpr (PRELOAD) nms_ldrows(wb_next, l, nrows, nTl);   // next chunk -> VGPR
    __builtin_amdgcn_sched_barrier(0);       // pin preload issue before chain
    const volatile u64* sp = sh + (B & 1) * NMSW;
    u64 curw = sp[0] | sp[1] | sp[2] | sp[3];
    // ---- chain (redundant per wave; wave-uniform fixpoint) ----
    u64 vm = readlane64(vreg, B);
    u64 ve = vm & ~curw;
    u64 D = 0ull, P = ve;
    while (D != P) {
        u64 nD = ve & ~__ballot((Tl & P) != 0ull);
        u64 nP = ve & ~__ballot((Tl & nD) != 0ull);
        D = nD; P = nP;
    }
    u64 kb = D;
    keep = (l == B) ? kb : keep;
    // ---- fold this wave's RPW pre-read rows (VALU only) ----
    u64 kbw = (kb >> (sw * RPW)) & 0xFFFFull;
    u64 p = 0ull;
#pragma unroll
    for (int k = 0; k < RPW; ++k)
        p |= rows[k] & (0ull - ((kbw >> k) & 1ull));
    remv |= p;
}

__global__ void __launch_bounds__(NMSW * 64, 1)
k_nms(const u64* __restrict__ mask,
      const u64* __restrict__ tdiag,
      const u64* __restrict__ validm,
      const float* __restrict__ sc,
      float* __restrict__ out) {
    __shared__ u64 ring[3 * SLOT_U64];      // 104,448 B staging ring
    __shared__ u64 sh[2 * NMSW];            // [parity][wave] exchange words
    int l  = threadIdx.x & 63;
    int sw = __builtin_amdgcn_readfirstlane((int)(threadIdx.x >> 6));
    u64 remv = 0ull;                        // partial: this wave's folded rows
    u64 keep = 0ull;                        // lane l = kb of chunk l (redundant)
    u64 vreg = validm[l];

    u64* wbs0 = ring + 0 * SLOT_U64 + (size_t)sw * WREG_U64;
    u64* wbs1 = ring + 1 * SLOT_U64 + (size_t)sw * WREG_U64;
    u64* wbs2 = ring + 2 * SLOT_U64 + (size_t)sw * WREG_U64;
    nms_stage(mask, tdiag, 0, sw, l, wbs0);
    nms_stage(mask, tdiag, 1, sw, l, wbs1);
    nms_stage(mask, tdiag, 2, sw, l, wbs2);
    __builtin_amdgcn_s_waitcnt(0x4F72);     // vmcnt(18): stage 0 complete
    __builtin_amdgcn_sched_barrier(0);
    __asm__ volatile("" ::: "memory");
    u64 rowA[RPW], rowB[RPW], TlA, TlB;
    nms_ldrows(wbs0, l, rowA, TlA);         // chunk 0 -> VGPR

    int sA = 0;                             // slot of the even chunk B
    for (int B = 0; B < 60; B += 2) {
        int s1 = sA + 1; if (s1 == 3) s1 = 0;
        int s2 = s1 + 1; if (s2 == 3) s2 = 0;
        u64* wbA = ring + (size_t)sA * SLOT_U64 + (size_t)sw * WREG_U64;
        u64* wbB = ring + (size_t)s1 * SLOT_U64 + (size_t)sw * WREG_U64;
        u64* wbC = ring + (size_t)s2 * SLOT_U64 + (size_t)sw * WREG_U64;
        nms_chunk<9, true, true>(B,     l, sw, rowA, TlA, rowB, TlB, wbA, wbB,
                                 vreg, sh, remv, keep, mask, tdiag);
        nms_chunk<9, true, true>(B + 1, l, sw, rowB, TlB, rowA, TlA, wbB, wbC,
                                 vreg, sh, remv, keep, mask, tdiag);
        sA = s2;
    }
    // epilogue: chunks 60..63 (sA == slot(60) == 0 here; 63 shares slot(60))
    {
        int s1 = sA + 1; if (s1 == 3) s1 = 0;
        int s2 = s1 + 1; if (s2 == 3) s2 = 0;
        u64* wb60 = ring + (size_t)sA * SLOT_U64 + (size_t)sw * WREG_U64;
        u64* wb61 = ring + (size_t)s1 * SLOT_U64 + (size_t)sw * WREG_U64;
        u64* wb62 = ring + (size_t)s2 * SLOT_U64 + (size_t)sw * WREG_U64;
        u64* wb63 = wb60;
        nms_chunk<9,  true,  true >(60, l, sw, rowA, TlA, rowB, TlB, wb60, wb61,
                                    vreg, sh, remv, keep, mask, tdiag);
        nms_chunk<9,  false, true >(61, l, sw, rowB, TlB, rowA, TlA, wb61, wb62,
                                    vreg, sh, remv, keep, mask, tdiag);
        nms_chunk<0,  false, true >(62, l, sw, rowA, TlA, rowB, TlB, wb62, wb63,
                                    vreg, sh, remv, keep, mask, tdiag);
        nms_chunk<-1, false, false>(63, l, sw, rowB, TlB, rowA, TlA, wb63, wb63,
                                    vreg, sh, remv, keep, mask, tdiag);
    }

    // epilogue: wave sw writes chunks RPW*sw .. +RPW-1
    for (int k = 0; k < RPW; ++k) {
        int c = sw * RPW + k;
        u64 kc = readlane64(keep, c);
        float s = sc[c * 64 + l];
        out[(size_t)(c * 64 + l) * 25 + 24] = ((kc >> l) & 1ull) ? s : 0.0f;
    }
}

extern "C" void kernel_launch(void* const* d_in, const int* in_sizes, int n_in,
                              void* d_out, int out_size, void* d_ws, size_t ws_size,
                              hipStream_t stream) {
    const float* anchors = (const float*)d_in[0];
    const float* psm_v   = (const float*)d_in[1];
    const float* rm_v    = (const float*)d_in[2];
    const float* psm_i   = (const float*)d_in[3];
    const float* rm_i    = (const float*)d_in[4];
    const float* tproj   = (const float*)d_in[5];
    const float* tego    = (const float*)d_in[6];
    float* out = (float*)d_out;
    char* ws = (char*)d_ws;

    u32*    keys    = (u32*)(ws + OFF_KEYS);
    u64*    mask    = (u64*)(ws + OFF_KEYS);    // reuse after keys consumed
    u32*    partial = (u32*)(ws + OFF_KEYS);    // rank partials (dead keys region)
    u32*    ghist   = (u32*)(ws + OFF_GHIST);
    u32*    ghist2  = (u32*)(ws + OFF_GHIST2);
    u32*    cnt     = (u32*)(ws + OFF_CNT);
    u32*    done    = (u32*)(ws + OFF_CNT + 4); // zeroed with cnt pad
    u64*    validm  = (u64*)(ws + OFF_VALIDM);
    u64*    cand    = (u64*)(ws + OFF_CAND);
    float4* stand   = (float4*)(ws + OFF_STAND);   // overlays cand (sequential-safe)
    u32*    sel_idx = (u32*)(ws + OFF_SELIDX);
    float*  sel_sc  = (float*)(ws + OFF_SELSC);
    u64*    tdiag   = (u64*)(ws + OFF_TDIAG);

    hipMemsetAsync(ws + OFF_GHIST, 0, ZERO_BYTES, stream);
    k_keys    <<<NT / 1024, 1024, 0, stream>>>(psm_v, psm_i, keys, ghist);
    k_hist2   <<<NT / 1024, 1024, 0, stream>>>(ghist, keys, ghist2);
    k_collect <<<NT / 1024, 1024, 0, stream>>>(ghist, ghist2, keys, cand, cnt);
    k_rank1   <<<dim3(32, RANK_J), 256, 0, stream>>>(cand, cnt, partial, done, sel_idx);
    k_boxes   <<<TOPK / 64, 64, 0, stream>>>(anchors, psm_v, psm_i, rm_v, rm_i,
                                             tproj, tego, sel_idx, sel_sc, out,
                                             stand, validm);
    k_maskdiag<<<1040, 256, 0, stream>>>(stand, mask, tdiag);
    k_nms     <<<1, NMSW * 64, 0, stream>>>(mask, tdiag, validm, sel_sc, out);
}

// Round 7
// 235.711 us; speedup vs baseline: 1.1418x; 1.1418x over previous
//
#include <hip/hip_runtime.h>
#include <stdint.h>

typedef unsigned int u32;
typedef unsigned long long u64;

#define HH 256
#define WW 512
#define HW (HH*WW)          // 131072
#define N2 (2*HW)           // 262144 per branch
#define NT (2*N2)           // 524288 total boxes
#define TOPK 4096
#define SCORE_THR 0.2f
#define NMS_THR 0.15f

// ---- workspace layout (bytes) ----
// [0, 2MB)  keys -> reused as rank partials (256 KB) -> reused as NMS mask
#define OFF_KEYS   0ull
#define OFF_GHIST  ((size_t)NT*4)                  // u32[1024] = 4 KB @ 2,097,152
#define OFF_GHIST2 (OFF_GHIST + 4096)              // u32[1024] = 4 KB
#define OFF_CNT    (OFF_GHIST2 + 4096)             // u32 (+pad 16)
#define OFF_VALIDM (OFF_CNT + 16)                  // u64[64] = 512 B
#define OFF_CAND   (OFF_VALIDM + 512)              // u64[8192] = 64 KB
#define OFF_STAND  OFF_CAND                        // float4[4096] overlays cand
#define OFF_SELIDX (OFF_CAND + 65536)              // u32[4096]
#define OFF_SELSC  (OFF_SELIDX + (size_t)TOPK*4)   // f32[4096]
#define OFF_TDIAG  (OFF_SELSC + (size_t)TOPK*4)    // u64[4096] = 32 KB @ 2,204,176
// end = 2,236,944 B < 2,261,008 proven in R6/R8
#define ZERO_BYTES (4096 + 4096 + 16)              // ghist + ghist2 + cnt
#define RANK_J 8                                   // j-slices for rank counting

// k_nms staging geometry
#define NMSW 4                                     // waves
#define RPW 16                                     // rows per wave
#define WREG_U64 1088                              // per-wave region: 1024 rows + 64 tdiag
#define SLOT_U64 (NMSW * WREG_U64)                 // 4352 u64 = 34 KB per ring slot

// orderable key for float (descending sortable as unsigned)
__device__ __forceinline__ u32 f2ord(float f) {
    u32 b = __float_as_uint(f);
    return (b & 0x80000000u) ? ~b : (b | 0x80000000u);
}

// ---------------- K1: scores -> keys + per-block LDS hist1 -> global -------
__global__ void __launch_bounds__(1024) k_keys(const float* __restrict__ psm_v,
                                               const float* __restrict__ psm_i,
                                               u32* __restrict__ keys,
                                               u32* __restrict__ ghist) {
    __shared__ u32 lh[1024];
    int t = threadIdx.x;
    lh[t] = 0;
    __syncthreads();
    int n = blockIdx.x * 1024 + t;
    int br = n >> 18;
    int m  = n & (N2 - 1);
    int a  = m & 1;
    int hw = m >> 1;
    const float* psm = br ? psm_i : psm_v;
    float x = psm[a * HW + hw];
    float s = 1.0f / (1.0f + __builtin_expf(-x));   // mirror ref f32 sigmoid
    u32 key = 0u;
    if (s > SCORE_THR) key = f2ord(s);
    keys[n] = key;
    if (key) atomicAdd(&lh[key >> 22], 1u);
    __syncthreads();
    u32 c = lh[t];
    if (c) atomicAdd(&ghist[t], c);
}

// Wave-0 suffix-scan pivot over a 1024-entry count array (16 entries/lane).
// suffix(b) non-increasing -> unique crossing (lane,j) writes result (race-free).
__device__ __forceinline__ void pivot1024(const u32* __restrict__ arr, u32 target,
                                          u32* out_bin, u32* out_next, int l) {
    u32 h[16], loc[16];
#pragma unroll
    for (int j = 0; j < 16; ++j) h[j] = arr[l * 16 + j];
    loc[15] = h[15];
#pragma unroll
    for (int j = 14; j >= 0; --j) loc[j] = loc[j + 1] + h[j];
    u32 T = loc[0];
    u32 incl = T;
#pragma unroll
    for (int d = 1; d < 64; d <<= 1) {
        u32 v = __shfl_down(incl, d);
        if (l + d < 64) incl += v;
    }
    u32 E = incl - T;                      // sum over lanes > l
#pragma unroll
    for (int j = 0; j < 16; ++j) {
        u32 S  = loc[j] + E;
        u32 Sn = (j < 15 ? loc[j + 1] : 0u) + E;
        if (S >= target && Sn < target) {
            *out_bin = (u32)(l * 16 + j);
            *out_next = Sn;
        }
    }
}

// ---------------- K2: hist2 over key>>12 within pivot-1 bin (512 blocks) ----
__global__ void __launch_bounds__(1024) k_hist2(const u32* __restrict__ ghist,
                                                const u32* __restrict__ keys,
                                                u32* __restrict__ ghist2) {
    __shared__ u32 lh[1024];
    __shared__ u32 b1_sh;
    int tid = threadIdx.x;
    lh[tid] = 0;
    if (tid < 64) {
        u32 bin = 0xFFFFFFFFu, nxt = 0;
        pivot1024(ghist, (u32)TOPK, &bin, &nxt, tid);
        if (bin != 0xFFFFFFFFu) b1_sh = bin;    // winner-lane writes
    }
    __syncthreads();
    u32 b1 = b1_sh;
    int n = blockIdx.x * 1024 + tid;
    u32 key = keys[n];
    if ((key >> 22) == b1) atomicAdd(&lh[(key >> 12) & 1023u], 1u);
    __syncthreads();
    u32 c = lh[tid];
    if (c) atomicAdd(&ghist2[tid], c);
}

// ---------------- K3: compact at 20-bit cut (512 blocks) --------------------
__global__ void __launch_bounds__(1024) k_collect(const u32* __restrict__ ghist,
                                                  const u32* __restrict__ ghist2,
                                                  const u32* __restrict__ keys,
                                                  u64* __restrict__ cand,
                                                  u32* __restrict__ cnt) {
    __shared__ u32 b1_sh, t2_sh, b2_sh;
    int tid = threadIdx.x;
    if (tid < 64) {
        u32 bin = 0xFFFFFFFFu, nxt = 0;
        pivot1024(ghist, (u32)TOPK, &bin, &nxt, tid);
        if (bin != 0xFFFFFFFFu) { b1_sh = bin; t2_sh = (u32)TOPK - nxt; }
    }
    __syncthreads();
    if (tid < 64) {
        u32 bin = 0xFFFFFFFFu, nxt = 0;
        pivot1024(ghist2, t2_sh, &bin, &nxt, tid);
        if (bin != 0xFFFFFFFFu) b2_sh = bin;
    }
    __syncthreads();
    u32 thr20 = (b1_sh << 10) | b2_sh;
    int n = blockIdx.x * 1024 + tid;
    u32 key = keys[n];
    if ((key >> 12) >= thr20) {
        u32 pos = atomicAdd(cnt, 1u);
        if (pos < 8192u)
            cand[pos] = ((u64)key << 32) | (u64)(u32)(~(u32)n);
    }
}

// ---------------- K4a: partial rank counts, (32 x RANK_J) blocks ------------
__global__ void __launch_bounds__(256) k_rank1(const u64* __restrict__ cand,
                                               const u32* __restrict__ cnt,
                                               u32* __restrict__ partial) {
    __shared__ u64 tile[1024];
    int tid = threadIdx.x;
    int i = blockIdx.x * 256 + tid;
    u32 base = blockIdx.y * 1024u;
    u32 c = *cnt;
    if (c > 8192u) c = 8192u;
    u64 my = (i < (int)c) ? cand[i] : 0ull;
#pragma unroll
    for (int k = 0; k < 4; ++k) {
        u32 idx = base + tid + k * 256;
        tile[tid + k * 256] = (idx < c) ? cand[idx] : 0ull;
    }
    __syncthreads();
    u32 lim = (c > base) ? ((c - base < 1024u) ? (c - base) : 1024u) : 0u;
    u32 r = 0;
#pragma unroll 4
    for (u32 k = 0; k < lim; ++k) r += (tile[k] > my) ? 1u : 0u;
    partial[blockIdx.y * 8192 + i] = r;
}

// ---------------- K4b: sum partials, scatter selected indices by rank -------
__global__ void __launch_bounds__(256) k_scatter(const u64* __restrict__ cand,
                                                 const u32* __restrict__ cnt,
                                                 const u32* __restrict__ partial,
                                                 u32* __restrict__ sel_idx) {
    int i = blockIdx.x * 256 + threadIdx.x;
    u32 c = *cnt;
    if (c > 8192u) c = 8192u;
    if (i >= (int)c) return;
    u32 rank = 0;
#pragma unroll
    for (int bj = 0; bj < RANK_J; ++bj) rank += partial[bj * 8192 + i];
    if (rank < (u32)TOPK) {
        u64 my = cand[i];
        sel_idx[rank] = ~((u32)(my & 0xFFFFFFFFull));
    }
}

// ---------------- box math helpers (mirror the jax reference) ---------------
__device__ __forceinline__ void box_corners(const float b[7], float cx[8], float cy[8], float cz[8]) {
    const float sx[8] = {0.5f,0.5f,-0.5f,-0.5f,0.5f,0.5f,-0.5f,-0.5f};
    const float sy[8] = {0.5f,-0.5f,-0.5f,0.5f,0.5f,-0.5f,-0.5f,0.5f};
    const float sz[8] = {-0.5f,-0.5f,-0.5f,-0.5f,0.5f,0.5f,0.5f,0.5f};
    float c = __builtin_cosf(b[6]), s = __builtin_sinf(b[6]);
#pragma unroll
    for (int k = 0; k < 8; k++) {
        float x = b[5] * sx[k], y = b[4] * sy[k], z = b[3] * sz[k];
        cx[k] = x * c - y * s + b[0];
        cy[k] = x * s + y * c + b[1];
        cz[k] = z + b[2];
    }
}

__device__ __forceinline__ void proj_T(const float* __restrict__ T, float cx[8], float cy[8], float cz[8]) {
#pragma unroll
    for (int k = 0; k < 8; k++) {
        float x = cx[k], y = cy[k], z = cz[k];
        cx[k] = T[0] * x + T[1] * y + T[2]  * z + T[3];
        cy[k] = T[4] * x + T[5] * y + T[6]  * z + T[7];
        cz[k] = T[8] * x + T[9] * y + T[10] * z + T[11];
    }
}

__device__ __forceinline__ void corner_to_center(const float cx[8], const float cy[8], const float cz[8], float b[7]) {
    float mx = 0.f, my = 0.f, mz = 0.f;
#pragma unroll
    for (int k = 0; k < 8; k++) { mx += cx[k]; my += cy[k]; mz += cz[k]; }
    mx *= 0.125f; my *= 0.125f; mz *= 0.125f;
    float htop = (cz[4] + cz[5] + cz[6] + cz[7]) * 0.25f;
    float hbot = (cz[0] + cz[1] + cz[2] + cz[3]) * 0.25f;
    const int lA[4] = {0,1,4,5}, lB[4] = {3,2,7,6};
    const int wA[4] = {0,3,4,7}, wB[4] = {1,2,5,6};
    float l = 0.f, w = 0.f, dx = 0.f, dy = 0.f;
#pragma unroll
    for (int i = 0; i < 4; i++) {
        float ax = cx[lA[i]] - cx[lB[i]];
        float ay = cy[lA[i]] - cy[lB[i]];
        l += __builtin_sqrtf(ax * ax + ay * ay);
        dx += ax; dy += ay;
    }
#pragma unroll
    for (int i = 0; i < 4; i++) {
        float ax = cx[wA[i]] - cx[wB[i]];
        float ay = cy[wA[i]] - cy[wB[i]];
        w += __builtin_sqrtf(ax * ax + ay * ay);
    }
    b[0] = mx; b[1] = my; b[2] = mz;
    b[3] = htop - hbot;
    b[4] = w * 0.25f;
    b[5] = l * 0.25f;
    b[6] = atan2f(dy, dx);
}

// ---------------- K5: decode boxes -> out corners + standup + validm --------
__global__ void __launch_bounds__(256) k_boxes(const float* __restrict__ anchors,
                                               const float* __restrict__ psm_v,
                                               const float* __restrict__ psm_i,
                                               const float* __restrict__ rm_v,
                                               const float* __restrict__ rm_i,
                                               const float* __restrict__ tproj,
                                               const float* __restrict__ tego,
                                               const u32* __restrict__ sel_idx,
                                               float* __restrict__ sel_sc,
                                               float* __restrict__ out,
                                               float4* __restrict__ stand,
                                               u64* __restrict__ validm) {
    int k = blockIdx.x * blockDim.x + threadIdx.x;
    if (k >= TOPK) return;
    int n = (int)(sel_idx[k] & (u32)(NT - 1));
    int br = n >> 18;
    int m  = n & (N2 - 1);
    int a  = m & 1;
    int hw = m >> 1;

    const float* psm = br ? psm_i : psm_v;
    float xs = psm[a * HW + hw];
    float s  = 1.0f / (1.0f + __builtin_expf(-xs));
    sel_sc[k] = (s > SCORE_THR) ? s : -1.0f;
    u64 vbits = __ballot(s > SCORE_THR);
    if ((threadIdx.x & 63) == 0) validm[k >> 6] = vbits;   // one word per wave

    const float* rm = br ? rm_i : rm_v;
    float d[7];
#pragma unroll
    for (int j = 0; j < 7; j++) d[j] = rm[(a * 7 + j) * HW + hw];
    const float* anc = anchors + (size_t)m * 7;
    float a0 = anc[0], a1 = anc[1], a2 = anc[2], a3 = anc[3], a4 = anc[4], a5 = anc[5], a6 = anc[6];
    float ad = __builtin_sqrtf(a4 * a4 + a5 * a5);
    float b[7];
    b[0] = d[0] * ad + a0;
    b[1] = d[1] * ad + a1;
    b[2] = d[2] * a3 + a2;
    b[3] = __builtin_expf(d[3]) * a3;
    b[4] = __builtin_expf(d[4]) * a4;
    b[5] = __builtin_expf(d[5]) * a5;
    b[6] = d[6] + a6;

    if (br) {  // infrared branch: corners -> t_proj -> back to center form
        float cx[8], cy[8], cz[8];
        box_corners(b, cx, cy, cz);
        proj_T(tproj, cx, cy, cz);
        corner_to_center(cx, cy, cz, b);
    }

    float cx[8], cy[8], cz[8];
    box_corners(b, cx, cy, cz);
    proj_T(tego, cx, cy, cz);

    float mnx = cx[0], mny = cy[0], mxx = cx[0], mxy = cy[0];
#pragma unroll
    for (int c = 0; c < 8; c++) {
        out[(size_t)k * 25 + c * 3 + 0] = cx[c];
        out[(size_t)k * 25 + c * 3 + 1] = cy[c];
        out[(size_t)k * 25 + c * 3 + 2] = cz[c];
        mnx = fminf(mnx, cx[c]); mny = fminf(mny, cy[c]);
        mxx = fmaxf(mxx, cx[c]); mxy = fmaxf(mxy, cy[c]);
    }
    stand[k] = make_float4(mnx, mny, mxx, mxy);
}

// ---------------- K6: suppression bitmask (4 rows per 256-thr block) --------
__global__ void __launch_bounds__(256) k_mask(const float4* __restrict__ stand,
                                              u64* __restrict__ mask) {
    int i = blockIdx.x * 4 + (threadIdx.x >> 6);
    int t = threadIdx.x & 63;
    int w0 = i >> 6;                    // chunks below diagonal are all-zero
    float4 bi = stand[i];
    float areai = (bi.z - bi.x) * (bi.w - bi.y);
    u64 myword = 0ull;
    for (int w = w0; w < 64; ++w) {
        int j = w * 64 + t;
        float4 bj = stand[j];
        float areaj = (bj.z - bj.x) * (bj.w - bj.y);
        float ltx = fmaxf(bi.x, bj.x), lty = fmaxf(bi.y, bj.y);
        float rbx = fminf(bi.z, bj.z), rby = fminf(bi.w, bj.w);
        float iw = fmaxf(rbx - ltx, 0.0f), ih = fmaxf(rby - lty, 0.0f);
        float inter = iw * ih;
        float iou = inter / (areai + areaj - inter + 1e-6f);
        bool sup = (iou > NMS_THR) && (j > i);
        u64 bits = __ballot(sup);
        if (t == w) myword = bits;
    }
    mask[(size_t)i * 64 + t] = myword;
}

// ---------------- K7: transposed intra-chunk suppression words --------------
__global__ void __launch_bounds__(64) k_diag(const float4* __restrict__ stand,
                                             u64* __restrict__ tdiag) {
    __shared__ float4 sb[64];
    int B = blockIdx.x, l = threadIdx.x;
    float4 me = stand[B * 64 + l];
    sb[l] = me;
    __syncthreads();
    float aream = (me.z - me.x) * (me.w - me.y);
    u64 T = 0ull;
    for (int j = 0; j < 64; ++j) {
        float4 bj = sb[j];                       // suppressor candidate
        float areaj = (bj.z - bj.x) * (bj.w - bj.y);
        float ltx = fmaxf(bj.x, me.x), lty = fmaxf(bj.y, me.y);
        float rbx = fminf(bj.z, me.z), rby = fminf(bj.w, me.w);
        float iw = fmaxf(rbx - ltx, 0.0f), ih = fmaxf(rby - lty, 0.0f);
        float inter = iw * ih;
        float iou = inter / (areaj + aream - inter + 1e-6f);
        bool sup = (iou > NMS_THR) && (j < l);
        T |= sup ? (1ull << j) : 0ull;
    }
    tdiag[B * 64 + l] = T;
}

// ---------------- K8: 4-wave greedy NMS, LDS ring + VGPR preload (v7) -------
// v5 (59.3us): all 21 LDS reads issued post-barrier on the serial path.
// v6 (72.4us, REGRESSION): preload ds_reads issued BEFORE the sp exchange
// reads -> in-order lgkm retirement made curw wait for all 17 preloads.
// v7: sp reads issued FIRST after the barrier (their counted wait is ~120cy),
// THEN refill(B+3) + preload rows(B+1)->VGPR are issued; the compiler's
// precise waitcnt (lgkmcnt(17)) lets the chain start while preloads retire
// under the chain+fold VALU. vmcnt(9): stage(B+1) resident before preload.
__device__ __forceinline__ u64 readlane64(u64 v, int lane) {
    u32 lo = (u32)__builtin_amdgcn_readlane((int)(u32)v, lane);
    u32 hi = (u32)__builtin_amdgcn_readlane((int)(u32)(v >> 32), lane);
    return ((u64)hi << 32) | (u64)lo;
}

__device__ __forceinline__ void nms_stage(const u64* __restrict__ mask,
                                          const u64* __restrict__ tdiag,
                                          int c, int sw, int l, u64* wb) {
    // lane l covers words 2(l&31), 2(l&31)+1; both < c -> provably zero, skip
    bool act = (2 * (l & 31) + 1) >= c;
    const u64* gb = mask + (size_t)c * 4096 + (size_t)(sw * RPW) * 64 + (size_t)l * 2;
    if (act) {
#pragma unroll
        for (int k = 0; k < 8; ++k) {
            __builtin_amdgcn_global_load_lds(
                (const __attribute__((address_space(1))) void*)(gb + (size_t)k * 128),
                (__attribute__((address_space(3))) void*)(wb + (size_t)k * 128), 16, 0, 0);
        }
    }
    if (l < 32) {   // tdiag row c (512B) contiguous into wb+1024
        __builtin_amdgcn_global_load_lds(
            (const __attribute__((address_space(1))) void*)(tdiag + (size_t)c * 64 + (size_t)l * 2),
            (__attribute__((address_space(3))) void*)(wb + 1024), 16, 0, 0);
    }
}

__device__ __forceinline__ void nms_ldrows(const u64* wb, int l,
                                           u64 (&rows)[RPW], u64& Tl) {
    Tl = wb[1024 + l];
#pragma unroll
    for (int k = 0; k < RPW; ++k) rows[k] = wb[(size_t)k * 64 + l];
}

// VMC: 9 = steady-state (stage B+1 done, B+2 in flight), 0 = drain, -1 = none
template<int VMC, bool REFILL, bool PRELOAD>
__device__ __forceinline__ void nms_chunk(int B, int l, int sw,
                                          const u64 (&rows)[RPW], u64 Tl,
                                          u64 (&nrows)[RPW], u64& nTl,
                                          u64* wb_cur, u64* wb_next,
                                          u64 vreg, volatile u64* sh,
                                          u64& remv, u64& keep,
                                          const u64* __restrict__ mask,
                                          const u64* __restrict__ tdiag) {
    // ---- exchange write: partial remv word for chunk B ----
    u64 x = readlane64(remv, B);
    if (l == 0) sh[(B & 1) * NMSW + sw] = x;
    __asm__ volatile("" ::: "memory");
    __builtin_amdgcn_s_waitcnt(0xC07F);      // lgkmcnt(0): ds_write committed
    __builtin_amdgcn_s_barrier();            // raw barrier: NO vmcnt drain
    __asm__ volatile("" ::: "memory");
    // ---- sp reads FIRST: nothing ahead of them in the lgkm queue ----
    const volatile u64* sp = sh + (B & 1) * NMSW;
    u64 c0 = sp[0], c1 = sp[1], c2 = sp[2], c3 = sp[3];
    // ---- DMA wait, then issue refill + preload (behind sp in lgkm order) ----
    if constexpr (VMC == 9) __builtin_amdgcn_s_waitcnt(0x0F79);  // vmcnt(9)
    else if constexpr (VMC == 0) __builtin_amdgcn_s_waitcnt(0x0F70);
    __builtin_amdgcn_sched_barrier(0);
    if constexpr (REFILL) nms_stage(mask, tdiag, B + 3, sw, l, wb_cur);
    if constexpr (PRELOAD) nms_ldrows(wb_next, l, nrows, nTl);   // -> VGPR
    __builtin_amdgcn_sched_barrier(0);       // pin preload issue before chain
    u64 curw = c0 | c1 | c2 | c3;            // counted wait: sp reads only
    // ---- chain (redundant per wave; wave-uniform fixpoint; VGPR inputs) ----
    u64 vm = readlane64(vreg, B);
    u64 ve = vm & ~curw;
    u64 D = 0ull, P = ve;
    while (D != P) {
        u64 nD = ve & ~__ballot((Tl & P) != 0ull);
        u64 nP = ve & ~__ballot((Tl & nD) != 0ull);
        D = nD; P = nP;
    }
    u64 kb = D;
    keep = (l == B) ? kb : keep;
    // ---- fold this wave's RPW pre-read rows (VALU only) ----
    u64 kbw = (kb >> (sw * RPW)) & 0xFFFFull;
    u64 p = 0ull;
#pragma unroll
    for (int k = 0; k < RPW; ++k)
        p |= rows[k] & (0ull - ((kbw >> k) & 1ull));
    remv |= p;
}

__global__ void __launch_bounds__(NMSW * 64, 1)
k_nms(const u64* __restrict__ mask,
      const u64* __restrict__ tdiag,
      const u64* __restrict__ validm,
      const float* __restrict__ sc,
      float* __restrict__ out) {
    __shared__ u64 ring[3 * SLOT_U64];      // 104,448 B staging ring
    __shared__ u64 sh[2 * NMSW];            // [parity][wave] exchange words
    int l  = threadIdx.x & 63;
    int sw = __builtin_amdgcn_readfirstlane((int)(threadIdx.x >> 6));
    u64 remv = 0ull;                        // partial: this wave's folded rows
    u64 keep = 0ull;                        // lane l = kb of chunk l (redundant)
    u64 vreg = validm[l];

    u64* wbs0 = ring + 0 * SLOT_U64 + (size_t)sw * WREG_U64;
    u64* wbs1 = ring + 1 * SLOT_U64 + (size_t)sw * WREG_U64;
    u64* wbs2 = ring + 2 * SLOT_U64 + (size_t)sw * WREG_U64;
    nms_stage(mask, tdiag, 0, sw, l, wbs0);
    nms_stage(mask, tdiag, 1, sw, l, wbs1);
    nms_stage(mask, tdiag, 2, sw, l, wbs2);
    __builtin_amdgcn_s_waitcnt(0x4F72);     // vmcnt(18): stage 0 complete
    __builtin_amdgcn_sched_barrier(0);
    __asm__ volatile("" ::: "memory");
    u64 rowA[RPW], rowB[RPW], TlA, TlB;
    nms_ldrows(wbs0, l, rowA, TlA);         // chunk 0 -> VGPR

    int sA = 0;                             // slot of the even chunk B
    for (int B = 0; B < 60; B += 2) {
        int s1 = sA + 1; if (s1 == 3) s1 = 0;
        int s2 = s1 + 1; if (s2 == 3) s2 = 0;
        u64* wbA = ring + (size_t)sA * SLOT_U64 + (size_t)sw * WREG_U64;
        u64* wbB = ring + (size_t)s1 * SLOT_U64 + (size_t)sw * WREG_U64;
        u64* wbC = ring + (size_t)s2 * SLOT_U64 + (size_t)sw * WREG_U64;
        nms_chunk<9, true, true>(B,     l, sw, rowA, TlA, rowB, TlB, wbA, wbB,
                                 vreg, sh, remv, keep, mask, tdiag);
        nms_chunk<9, true, true>(B + 1, l, sw, rowB, TlB, rowA, TlA, wbB, wbC,
                                 vreg, sh, remv, keep, mask, tdiag);
        sA = s2;
    }
    // epilogue: chunks 60..63 (slot(60)=0; 63 shares slot 0)
    {
        int s1 = sA + 1; if (s1 == 3) s1 = 0;
        int s2 = s1 + 1; if (s2 == 3) s2 = 0;
        u64* wb60 = ring + (size_t)sA * SLOT_U64 + (size_t)sw * WREG_U64;
        u64* wb61 = ring + (size_t)s1 * SLOT_U64 + (size_t)sw * WREG_U64;
        u64* wb62 = ring + (size_t)s2 * SLOT_U64 + (size_t)sw * WREG_U64;
        u64* wb63 = wb60;
        nms_chunk<9,  true,  true >(60, l, sw, rowA, TlA, rowB, TlB, wb60, wb61,
                                    vreg, sh, remv, keep, mask, tdiag);
        nms_chunk<9,  false, true >(61, l, sw, rowB, TlB, rowA, TlA, wb61, wb62,
                                    vreg, sh, remv, keep, mask, tdiag);
        nms_chunk<0,  false, true >(62, l, sw, rowA, TlA, rowB, TlB, wb62, wb63,
                                    vreg, sh, remv, keep, mask, tdiag);
        nms_chunk<-1, false, false>(63, l, sw, rowB, TlB, rowA, TlA, wb63, wb63,
                                    vreg, sh, remv, keep, mask, tdiag);
    }

    // epilogue: wave sw writes chunks RPW*sw .. +RPW-1
    for (int k = 0; k < RPW; ++k) {
        int c = sw * RPW + k;
        u64 kc = readlane64(keep, c);
        float s = sc[c * 64 + l];
        out[(size_t)(c * 64 + l) * 25 + 24] = ((kc >> l) & 1ull) ? s : 0.0f;
    }
}

extern "C" void kernel_launch(void* const* d_in, const int* in_sizes, int n_in,
                              void* d_out, int out_size, void* d_ws, size_t ws_size,
                              hipStream_t stream) {
    const float* anchors = (const float*)d_in[0];
    const float* psm_v   = (const float*)d_in[1];
    const float* rm_v    = (const float*)d_in[2];
    const float* psm_i   = (const float*)d_in[3];
    const float* rm_i    = (const float*)d_in[4];
    const float* tproj   = (const float*)d_in[5];
    const float* tego    = (const float*)d_in[6];
    float* out = (float*)d_out;
    char* ws = (char*)d_ws;

    u32*    keys    = (u32*)(ws + OFF_KEYS);
    u64*    mask    = (u64*)(ws + OFF_KEYS);    // reuse after keys consumed
    u32*    partial = (u32*)(ws + OFF_KEYS);    // rank partials (dead keys region)
    u32*    ghist   = (u32*)(ws + OFF_GHIST);
    u32*    ghist2  = (u32*)(ws + OFF_GHIST2);
    u32*    cnt     = (u32*)(ws + OFF_CNT);
    u64*    validm  = (u64*)(ws + OFF_VALIDM);
    u64*    cand    = (u64*)(ws + OFF_CAND);
    float4* stand   = (float4*)(ws + OFF_STAND);   // overlays cand (sequential-safe)
    u32*    sel_idx = (u32*)(ws + OFF_SELIDX);
    float*  sel_sc  = (float*)(ws + OFF_SELSC);
    u64*    tdiag   = (u64*)(ws + OFF_TDIAG);

    hipMemsetAsync(ws + OFF_GHIST, 0, ZERO_BYTES, stream);
    k_keys   <<<NT / 1024, 1024, 0, stream>>>(psm_v, psm_i, keys, ghist);
    k_hist2  <<<NT / 1024, 1024, 0, stream>>>(ghist, keys, ghist2);
    k_collect<<<NT / 1024, 1024, 0, stream>>>(ghist, ghist2, keys, cand, cnt);
    k_rank1  <<<dim3(32, RANK_J), 256, 0, stream>>>(cand, cnt, partial);
    k_scatter<<<32, 256, 0, stream>>>(cand, cnt, partial, sel_idx);
    k_boxes  <<<TOPK / 256, 256, 0, stream>>>(anchors, psm_v, psm_i, rm_v, rm_i,
                                              tproj, tego, sel_idx, sel_sc, out,
                                              stand, validm);
    k_mask   <<<TOPK / 4, 256, 0, stream>>>(stand, mask);
    k_diag   <<<64, 64, 0, stream>>>(stand, tdiag);
    k_nms    <<<1, NMSW * 64, 0, stream>>>(mask, tdiag, validm, sel_sc, out);
}